// Round 7
// baseline (299.054 us; speedup 1.0000x reference)
//
#include <hip/hip_runtime.h>

#define N_ROWS 4096
#define IN_F   4096
#define OUT_F  4096
#define C_CB   256
#define KDIM   4096   // C_CB * 16

typedef short bf16x8 __attribute__((ext_vector_type(8)));
typedef float f32x4  __attribute__((ext_vector_type(4)));
typedef float f32x16 __attribute__((ext_vector_type(16)));

union ABFrag { unsigned long long u[2]; bf16x8 v; };

__device__ __forceinline__ unsigned int f2bf(float f) {
    unsigned int u = __builtin_bit_cast(unsigned int, f);
    return (u + 0x7FFFu + ((u >> 16) & 1u)) >> 16;   // RNE
}

// ---------------- Kernel 1: fused prep ----------------
// blocks [0, N_ROWS): tree descent, R3-proven LDS-staged gather form
// blocks [N_ROWS, N_ROWS+CVT_BLOCKS): lut fp32 -> bf16
// Single launch: the two independent passes run concurrently, one launch gap
// removed (R1/R4 measured the fused/fewer-launch residual at 8-17us vs 33-45).
#define CVT_BLOCKS ((OUT_F * KDIM) / (256 * 8))   // 8192

__global__ __launch_bounds__(256) void k_prep(const float* __restrict__ input,
                                              const int* __restrict__ dims,
                                              const float* __restrict__ thr,
                                              unsigned char* __restrict__ idx4,
                                              const float* __restrict__ lut,
                                              unsigned short* __restrict__ lutb) {
    __shared__ float rowS[IN_F];         // 16 KB
    __shared__ float thrS[C_CB * 15];    // 15 KB
    __shared__ int   dimS[C_CB * 4];     // 4 KB
    const int b = blockIdx.x;
    const int t = threadIdx.x;

    if (b < N_ROWS) {
        const int n = b;
        #pragma unroll
        for (int i = 0; i < 4; i++) dimS[i * 256 + t] = dims[i * 256 + t];
        #pragma unroll
        for (int i = 0; i < 15; i++) thrS[i * 256 + t] = thr[i * 256 + t];
        const float* row = input + (size_t)n * IN_F;
        #pragma unroll
        for (int i = 0; i < 4; i++) {
            float4 v = *(const float4*)(row + i * 1024 + t * 4);
            *(float4*)(rowS + i * 1024 + t * 4) = v;
        }
        __syncthreads();

        const int c = t;
        int4 d = *(const int4*)(dimS + c * 4);
        const float* th = thrS + c * 15;
        float x0 = rowS[d.x], x1 = rowS[d.y], x2 = rowS[d.z], x3 = rowS[d.w];
        int b0 = x0 > th[0];
        int j1 = 1 + b0;
        int b1 = x1 > th[j1];
        int j2 = 2 * j1 + 1 + b1;
        int b2 = x2 > th[j2];
        int j3 = 2 * j2 + 1 + b2;
        int b3 = x3 > th[j3];
        int idx = (b0 << 3) | (b1 << 2) | (b2 << 1) | b3;
        int other = __shfl_xor(idx, 1);
        if (!(c & 1))
            idx4[(c >> 1) * N_ROWS + n] = (unsigned char)(idx | (other << 4));
    } else {
        const int i = ((b - N_ROWS) * 256 + t) * 8;
        float4 a = *(const float4*)(lut + i);
        float4 f = *(const float4*)(lut + i + 4);
        uint4 o;
        o.x = f2bf(a.x) | (f2bf(a.y) << 16);
        o.y = f2bf(a.z) | (f2bf(a.w) << 16);
        o.z = f2bf(f.x) | (f2bf(f.y) << 16);
        o.w = f2bf(f.z) | (f2bf(f.w) << 16);
        *(uint4*)(lutb + i) = o;
    }
}

// ---------------- Kernel 2: GEMM with implicit one-hot A, 32x32x16 MFMA ----------------
// out[n][k] = sum_c lut[k][c][idx[n][c]]
// Shape switch 16x16x32 -> 32x32x16: matrix cycles/tile 310->258 (2382 vs 2075 TF
// ceiling), MFMA instruction count halves (shared issue port relief), A-build
// count unchanged. Layouts: A[m=lane&31][k=(lane>>5)*8+j], B[k][n=lane&31],
// C/D row=(reg&3)+8*(reg>>2)+4*(lane>>5), col=lane&31.
// Row permutation: m-subtile mi in {0,1}, MFMA row m <-> wave row 2m+mi, so one
// ds_read_u16 (2 bytes = rows 2m,2m+1; nibbles = 2 codebooks) serves 4 A-builds.
// Schedule = R6-proven: 2-deep dbuf, phase-split (s1 reads under s0 MFMAs),
// counted vmcnt(8) never 0 in-loop, setprio clusters, 2 barriers/tile.
#define BM 128
#define BN 256
#define BKT 64          // kdim per LDS stage (4 codebooks = 2 phases of 2)
#define BSTAGE (BN * BKT * 2)   // 32 KB per B buffer
#define NT (KDIM / BKT)         // 64 tiles

template<bool STAGE_FP32>
__global__ __launch_bounds__(256, 2) void k_gemm(const unsigned short* __restrict__ lutb,
                                                 const float* __restrict__ lutf,
                                                 const unsigned char* __restrict__ idx4,
                                                 float* __restrict__ out) {
    __shared__ unsigned char smem[8192 + 2 * BSTAGE];    // idx 8KB + 2x B 32KB = 72 KB
    unsigned char* ish  = smem;                          // [cbp 64][row 128] (half window)
    unsigned char* bsh0 = smem + 8192;
    unsigned char* bsh1 = smem + 8192 + BSTAGE;

    const int t   = threadIdx.x;
    const int r31 = t & 31;                // A row / B col within 32-subtile
    const int h   = (t >> 5) & 1;          // k-half of the wave
    const int w   = t >> 6;
    const int wm  = w >> 1, wn = w & 1;    // 2x2 waves -> 64x128 tile each

    // XCD swizzle: XCD = bid&7 owns 2 consecutive n-panels x all 32 m-blocks.
    const int bid = blockIdx.x;            // 512 blocks = 16 bx x 32 by
    const int bx  = ((bid & 7) << 1) | ((bid >> 3) & 1);   // n-block 0..15
    const int by  = bid >> 4;                              // m-block 0..31
    const int m0  = by * BM;
    const int n0  = bx * BN;

    // --- idx staging: half hh covers cbp [hh*64, hh*64+64) x rows [m0, m0+128) ---
    auto stageIdx = [&](int hh) {
        #pragma unroll
        for (int qq = 0; qq < 2; qq++) {
            int L = qq * 256 + t;          // 16B chunk: cbp = L>>3, row-part = L&7
            const unsigned char* g = idx4 + (size_t)(hh * 64 + (L >> 3)) * N_ROWS + m0 + (L & 7) * 16;
            __builtin_amdgcn_global_load_lds(
                (const __attribute__((address_space(1))) void*)g,
                (__attribute__((address_space(3))) void*)(ish + L * 16), 16, 0, 0);
        }
    };

    // --- B tile staging: [256 out-rows][64 kdim] bf16, chunk-XOR swizzled ---
    auto stageB = [&](unsigned char* dst, int kbn) {
        #pragma unroll
        for (int qq = 0; qq < 8; qq++) {
            int L = qq * 256 + t;               // 16B chunk index in LDS
            int r = L >> 3, p = L & 7;
            int c = p ^ (r & 7);                // global chunk stored at position p
            const unsigned short* g = lutb + (size_t)(n0 + r) * KDIM + kbn + c * 8;
            __builtin_amdgcn_global_load_lds(
                (const __attribute__((address_space(1))) void*)g,
                (__attribute__((address_space(3))) void*)(dst + L * 16), 16, 0, 0);
        }
    };
    auto stageB32 = [&](unsigned char* dst, int kbn) {
        #pragma unroll
        for (int qq = 0; qq < 8; qq++) {
            int L = qq * 256 + t;
            int r = L >> 3, p = L & 7;
            int c = p ^ (r & 7);
            const float* g = lutf + (size_t)(n0 + r) * KDIM + kbn + c * 8;
            float4 f0 = *(const float4*)g;
            float4 f1 = *(const float4*)(g + 4);
            uint4 o;
            o.x = f2bf(f0.x) | (f2bf(f0.y) << 16);
            o.y = f2bf(f0.z) | (f2bf(f0.w) << 16);
            o.z = f2bf(f1.x) | (f2bf(f1.y) << 16);
            o.w = f2bf(f1.z) | (f2bf(f1.w) << 16);
            *(uint4*)(dst + L * 16) = o;
        }
    };

    f32x16 acc[2][4];
    #pragma unroll
    for (int ms = 0; ms < 2; ms++)
        #pragma unroll
        for (int ns = 0; ns < 4; ns++)
            acc[ms][ns] = (f32x16){0.f,0.f,0.f,0.f,0.f,0.f,0.f,0.f,
                                   0.f,0.f,0.f,0.f,0.f,0.f,0.f,0.f};

    const int xorv = r31 & 7;                       // B chunk swizzle key (row&7)
    const int bBase = (wn * 128 + r31) * (BKT * 2); // B LDS row byte (nsub adds 32*128)
    const int aByte = wm * 64 + 2 * r31;            // idx u16 offset within a cbp row
    const unsigned int sub8 = h << 3;               // k-window offset of this half-wave

    // per-phase (one cbp = 2 codebooks) LDS->reg reads: 8 x ds_read_b128 + 1 x u16
    auto readPhase = [&](const unsigned char* src, int s, int kb,
                         ABFrag (&bf)[2][4], unsigned int& w16) {
        #pragma unroll
        for (int cb = 0; cb < 2; cb++) {
            const int chunkOff = ((s * 4 + cb * 2 + h) ^ xorv) * 16;
            #pragma unroll
            for (int ns = 0; ns < 4; ns++)
                bf[cb][ns].v = *(const bf16x8*)(src + bBase + ns * (32 * BKT * 2) + chunkOff);
        }
        w16 = *(const unsigned short*)(ish + ((((kb >> 5) + s) & 63) * 128) + aByte);
    };
    // per-phase MFMA cluster: 4 one-hot A builds (2 msub x 2 cb), 16 MFMAs
    auto mfmaPhase = [&](const ABFrag (&bf)[2][4], unsigned int w16) {
        #pragma unroll
        for (int cb = 0; cb < 2; cb++) {
            ABFrag af[2];
            #pragma unroll
            for (int ms = 0; ms < 2; ms++) {
                unsigned int T = (w16 >> (ms * 8 + cb * 4)) & 0xFu;
                unsigned int rel = T - sub8;                    // one-hot iff rel in [0,8)
                unsigned long long sh = 0x3F80ull << ((rel & 3) << 4);  // bf16 1.0
                af[ms].u[0] = (rel < 4u) ? sh : 0ull;
                af[ms].u[1] = ((rel - 4u) < 4u) ? sh : 0ull;
            }
            #pragma unroll
            for (int ms = 0; ms < 2; ms++)
                #pragma unroll
                for (int ns = 0; ns < 4; ns++)
                    acc[ms][ns] = __builtin_amdgcn_mfma_f32_32x32x16_bf16(
                        af[ms].v, bf[cb][ns].v, acc[ms][ns], 0, 0, 0);
        }
    };

    if (!STAGE_FP32) {
        // prologue: idx-half0(2) + stage0(8) + stage1(8); vmcnt(8) -> idx half0 and
        // stage0 complete, stage1's 8 still in flight.
        stageIdx(0);
        stageB(bsh0, 0);
        stageB(bsh1, BKT);
        asm volatile("s_waitcnt vmcnt(8)" ::: "memory");
        __builtin_amdgcn_s_barrier();
        __builtin_amdgcn_sched_barrier(0);

        unsigned char* cur = bsh0;
        unsigned char* nxt = bsh1;
        ABFrag bf0[2][4], bf1[2][4];
        unsigned int w0, w1;
        for (int tt = 0; tt < NT; tt++) {
            const int kb = tt * BKT;
            // [A0] s=0 reads
            readPhase(cur, 0, kb, bf0, w0);
            asm volatile("s_waitcnt lgkmcnt(0)" ::: "memory");
            __builtin_amdgcn_sched_barrier(0);
            // [D0] issue s=1 reads (no wait), then s=0 MFMA cluster over them
            readPhase(cur, 1, kb, bf1, w1);
            __builtin_amdgcn_sched_barrier(0);
            __builtin_amdgcn_s_setprio(1);
            mfmaPhase(bf0, w0);
            __builtin_amdgcn_s_setprio(0);
            asm volatile("s_waitcnt lgkmcnt(0)" ::: "memory");
            __builtin_amdgcn_sched_barrier(0);
            // [B] all waves done reading cur (and, at tt=31, ish half0) -> overwrite safe
            __builtin_amdgcn_s_barrier();
            __builtin_amdgcn_sched_barrier(0);
            // [C] restage: idx half1 (tt=31, issued FIRST so vmcnt(8) at [E] covers it),
            //     then B tile tt+2 (issue only)
            if (tt == 31) stageIdx(1);
            if (tt + 2 < NT) stageB(cur, kb + 2 * BKT);
            __builtin_amdgcn_sched_barrier(0);
            // [D1] s=1 MFMA cluster (stage loads fly underneath)
            __builtin_amdgcn_s_setprio(1);
            mfmaPhase(bf1, w1);
            __builtin_amdgcn_s_setprio(0);
            // [E] counted wait: tile tt+1's 8 loads (and idx half1 at tt=31) done;
            //     tt+2's 8 newest stay in flight
            if (tt + 2 < NT) asm volatile("s_waitcnt vmcnt(8)" ::: "memory");
            else             asm volatile("s_waitcnt vmcnt(0)" ::: "memory");
            // [F] writes visible to all waves before next iteration reads
            __builtin_amdgcn_s_barrier();
            __builtin_amdgcn_sched_barrier(0);
            unsigned char* tmp = cur; cur = nxt; nxt = tmp;
        }
    } else {
        // Fallback (no workspace for lutb): single-buffer loop, convert on stage.
        stageIdx(0);
        asm volatile("s_waitcnt vmcnt(0)" ::: "memory");
        __syncthreads();
        ABFrag bfx[2][4];
        unsigned int wx;
        for (int tt = 0; tt < NT; tt++) {
            const int kb = tt * BKT;
            if (tt == 32) stageIdx(1);          // prev sync: no readers of ish in flight
            stageB32(bsh0, kb);
            __syncthreads();                    // full drain covers global_load_lds too
            #pragma unroll
            for (int s = 0; s < 2; s++) {
                readPhase(bsh0, s, kb, bfx, wx);
                mfmaPhase(bfx, wx);
            }
            __syncthreads();
        }
    }

    // --- epilogue: C/D row m_r=(reg&3)+8*(reg>>2)+4*h -> global row m0+wm*64+2*m_r+ms ---
    #pragma unroll
    for (int ms = 0; ms < 2; ms++) {
        #pragma unroll
        for (int ns = 0; ns < 4; ns++) {
            const int col = n0 + wn * 128 + ns * 32 + r31;
            #pragma unroll
            for (int reg = 0; reg < 16; reg++) {
                const int mr  = (reg & 3) + 8 * (reg >> 2) + 4 * h;
                const int row = m0 + wm * 64 + 2 * mr + ms;
                out[(size_t)row * OUT_F + col] = acc[ms][ns][reg];
            }
        }
    }
}

extern "C" void kernel_launch(void* const* d_in, const int* in_sizes, int n_in,
                              void* d_out, int out_size, void* d_ws, size_t ws_size,
                              hipStream_t stream) {
    const float* input = (const float*)d_in[0];
    const int*   dims  = (const int*)d_in[1];
    // d_in[2] selection_matrix, d_in[4] tree_des_mat: structure folded into the kernels
    const float* thr   = (const float*)d_in[3];
    const float* lut   = (const float*)d_in[5];
    float* out = (float*)d_out;

    const size_t lutbBytes = (size_t)OUT_F * KDIM * 2;       // 32 MB
    const size_t idxBytes  = (size_t)(C_CB / 2) * N_ROWS;    // 512 KB

    const int nblocks = (OUT_F / BN) * (N_ROWS / BM);        // 16 x 32 = 512

    if (ws_size >= lutbBytes + idxBytes) {
        unsigned short* lutb = (unsigned short*)d_ws;
        unsigned char*  idx4 = (unsigned char*)d_ws + lutbBytes;
        k_prep<<<N_ROWS + CVT_BLOCKS, 256, 0, stream>>>(input, dims, thr, idx4, lut, lutb);
        k_gemm<false><<<nblocks, 256, 0, stream>>>(lutb, lut, idx4, out);
    } else {
        unsigned char* idx4 = (unsigned char*)d_ws;
        k_prep<<<N_ROWS, 256, 0, stream>>>(input, dims, thr, idx4, lut, nullptr);
        k_gemm<true><<<nblocks, 256, 0, stream>>>(nullptr, lut, idx4, out);
    }
}

// Round 9
// 290.597 us; speedup vs baseline: 1.0291x; 1.0291x over previous
//
#include <hip/hip_runtime.h>

#define N_ROWS 4096
#define IN_F   4096
#define OUT_F  4096
#define C_CB   256
#define KDIM   4096   // C_CB * 16

typedef short bf16x8 __attribute__((ext_vector_type(8)));
typedef float f32x4  __attribute__((ext_vector_type(4)));

union ABFrag { unsigned long long u[2]; bf16x8 v; };

__device__ __forceinline__ unsigned int f2bf(float f) {
    unsigned int u = __builtin_bit_cast(unsigned int, f);
    return (u + 0x7FFFu + ((u >> 16) & 1u)) >> 16;   // RNE
}

// ---------------- Kernel 1: fused prep ----------------
// blocks [0, N_ROWS): tree descent, R3-proven LDS-staged gather form
// blocks [N_ROWS, N_ROWS+CVT_BLOCKS): lut fp32 -> bf16
// Fused single launch measured ~11us cheaper than separate (R7 rest 33.8 vs R6 45.3).
#define CVT_BLOCKS ((OUT_F * KDIM) / (256 * 8))   // 8192

__global__ __launch_bounds__(256) void k_prep(const float* __restrict__ input,
                                              const int* __restrict__ dims,
                                              const float* __restrict__ thr,
                                              unsigned char* __restrict__ idx4,
                                              const float* __restrict__ lut,
                                              unsigned short* __restrict__ lutb) {
    __shared__ float rowS[IN_F];         // 16 KB
    __shared__ float thrS[C_CB * 15];    // 15 KB
    __shared__ int   dimS[C_CB * 4];     // 4 KB
    const int b = blockIdx.x;
    const int t = threadIdx.x;

    if (b < N_ROWS) {
        const int n = b;
        #pragma unroll
        for (int i = 0; i < 4; i++) dimS[i * 256 + t] = dims[i * 256 + t];
        #pragma unroll
        for (int i = 0; i < 15; i++) thrS[i * 256 + t] = thr[i * 256 + t];
        const float* row = input + (size_t)n * IN_F;
        #pragma unroll
        for (int i = 0; i < 4; i++) {
            float4 v = *(const float4*)(row + i * 1024 + t * 4);
            *(float4*)(rowS + i * 1024 + t * 4) = v;
        }
        __syncthreads();

        const int c = t;
        int4 d = *(const int4*)(dimS + c * 4);
        const float* th = thrS + c * 15;
        float x0 = rowS[d.x], x1 = rowS[d.y], x2 = rowS[d.z], x3 = rowS[d.w];
        int b0 = x0 > th[0];
        int j1 = 1 + b0;
        int b1 = x1 > th[j1];
        int j2 = 2 * j1 + 1 + b1;
        int b2 = x2 > th[j2];
        int j3 = 2 * j2 + 1 + b2;
        int b3 = x3 > th[j3];
        int idx = (b0 << 3) | (b1 << 2) | (b2 << 1) | b3;
        int other = __shfl_xor(idx, 1);
        if (!(c & 1))
            idx4[(c >> 1) * N_ROWS + n] = (unsigned char)(idx | (other << 4));
    } else {
        const int i = ((b - N_ROWS) * 256 + t) * 8;
        float4 a = *(const float4*)(lut + i);
        float4 f = *(const float4*)(lut + i + 4);
        uint4 o;
        o.x = f2bf(a.x) | (f2bf(a.y) << 16);
        o.y = f2bf(a.z) | (f2bf(a.w) << 16);
        o.z = f2bf(f.x) | (f2bf(f.y) << 16);
        o.w = f2bf(f.z) | (f2bf(f.w) << 16);
        *(uint4*)(lutb + i) = o;
    }
}

// ---------------- Kernel 2: GEMM with implicit one-hot A ----------------
// out[n][k] = sum_c lut[k][c][idx[n][c]]
// R6 core (16x16x32, wave-tile 64x128, 0 bank conflicts) + cross-tile s0
// prefetch with SOUND sync (round-8's [P]-before-retire race fixed):
//   - vmcnt(0) moved to pre-[B]: drains loads issued a FULL TILE earlier
//     (covered by [P]+[D1]+[A]+[D0] ~500cy) and makes tile tt+1 visible at
//     the barrier, so [P] may read it.
//   - single barrier per tile (was 2): [B] alone carries read-before-
//     overwrite (lgkm(0) before it) and staging visibility (vmcnt(0) before it).
//   - idx window full 16KB, staged once in prologue (no half-restage hazard);
//     80KB LDS = same 2 blocks/CU as 72KB.
#define BM 128
#define BN 256
#define BKT 64          // kdim per LDS stage (2 MFMA K-steps of 32)
#define BSTAGE (BN * BKT * 2)   // 32 KB per B buffer
#define NT (KDIM / BKT)         // 64 tiles

template<bool STAGE_FP32>
__global__ __launch_bounds__(256, 2) void k_gemm(const unsigned short* __restrict__ lutb,
                                                 const float* __restrict__ lutf,
                                                 const unsigned char* __restrict__ idx4,
                                                 float* __restrict__ out) {
    __shared__ unsigned char smem[16384 + 2 * BSTAGE];   // idx 16KB + 2x B 32KB = 80 KB
    unsigned char* ish  = smem;                          // [cbp 128][row 128]
    unsigned char* bsh0 = smem + 16384;
    unsigned char* bsh1 = smem + 16384 + BSTAGE;

    const int t   = threadIdx.x;
    const int l15 = t & 15;
    const int q   = (t >> 4) & 3;          // quad within wave
    const int w   = t >> 6;
    const int wm  = w >> 1, wn = w & 1;    // 2x2 waves -> 64x128 tile each

    // XCD swizzle: XCD = bid&7 owns 2 consecutive n-panels x all 32 m-blocks.
    const int bid = blockIdx.x;            // 512 blocks = 16 bx x 32 by
    const int bx  = ((bid & 7) << 1) | ((bid >> 3) & 1);   // n-block 0..15
    const int by  = bid >> 4;                              // m-block 0..31
    const int m0  = by * BM;
    const int n0  = bx * BN;

    // --- idx staging: full [cbp 128][row 128] window, once in prologue ---
    auto stageIdx = [&]() {
        #pragma unroll
        for (int qq = 0; qq < 4; qq++) {
            int L = qq * 256 + t;          // 16B chunk: cbp = L>>3, row-part = L&7
            const unsigned char* g = idx4 + (size_t)(L >> 3) * N_ROWS + m0 + (L & 7) * 16;
            __builtin_amdgcn_global_load_lds(
                (const __attribute__((address_space(1))) void*)g,
                (__attribute__((address_space(3))) void*)(ish + L * 16), 16, 0, 0);
        }
    };

    // --- B tile staging: [256 out-rows][64 kdim] bf16, chunk-XOR swizzled ---
    auto stageB = [&](unsigned char* dst, int kbn) {
        #pragma unroll
        for (int qq = 0; qq < 8; qq++) {
            int L = qq * 256 + t;               // 16B chunk index in LDS
            int r = L >> 3, p = L & 7;
            int c = p ^ (r & 7);                // global chunk stored at position p
            const unsigned short* g = lutb + (size_t)(n0 + r) * KDIM + kbn + c * 8;
            __builtin_amdgcn_global_load_lds(
                (const __attribute__((address_space(1))) void*)g,
                (__attribute__((address_space(3))) void*)(dst + L * 16), 16, 0, 0);
        }
    };
    auto stageB32 = [&](unsigned char* dst, int kbn) {
        #pragma unroll
        for (int qq = 0; qq < 8; qq++) {
            int L = qq * 256 + t;
            int r = L >> 3, p = L & 7;
            int c = p ^ (r & 7);
            const float* g = lutf + (size_t)(n0 + r) * KDIM + kbn + c * 8;
            float4 f0 = *(const float4*)g;
            float4 f1 = *(const float4*)(g + 4);
            uint4 o;
            o.x = f2bf(f0.x) | (f2bf(f0.y) << 16);
            o.y = f2bf(f0.z) | (f2bf(f0.w) << 16);
            o.z = f2bf(f1.x) | (f2bf(f1.y) << 16);
            o.w = f2bf(f1.z) | (f2bf(f1.w) << 16);
            *(uint4*)(dst + L * 16) = o;
        }
    };

    f32x4 acc[4][8];
    #pragma unroll
    for (int mi = 0; mi < 4; mi++)
        #pragma unroll
        for (int ni = 0; ni < 8; ni++)
            acc[mi][ni] = (f32x4){0.f, 0.f, 0.f, 0.f};

    const int xorv = l15 & 7;                       // B chunk swizzle key
    const int bRowByte = (wn * 128 + l15) * (BKT * 2);
    const int aByte = wm * 64 + l15 * 4;            // idx word offset within a cbp row
    const int qh4  = (q >> 1) * 4;                  // nibble select: cb c0 vs c0+1
    const unsigned int sub8 = (q & 1) << 3;         // window offset within codebook

    // B fragment reads for phase s: 8 x ds_read_b128 (swizzled chunk)
    auto bfRead = [&](const unsigned char* src, int s, ABFrag (&bf)[8]) {
        const int chunkOff = ((s * 4 + q) ^ xorv) * 16;
        #pragma unroll
        for (int ni = 0; ni < 8; ni++)
            bf[ni].v = *(const bf16x8*)(src + bRowByte + ni * (16 * BKT * 2) + chunkOff);
    };
    // idx word for phase s of tile at kb (full window: cbp in [0,128))
    auto wRead = [&](int kb, int s) {
        return *(const unsigned int*)(ish + ((kb >> 5) + s) * 128 + aByte);
    };
    // per-phase MFMA cluster: build 4 one-hot A frags, 32 MFMAs
    auto mfmaPhase = [&](const ABFrag (&bf)[8], unsigned int w32) {
        ABFrag af[4];
        #pragma unroll
        for (int mi = 0; mi < 4; mi++) {
            unsigned int T = (w32 >> (mi * 8 + qh4)) & 0xFu;
            unsigned int rel = T - sub8;                    // one-hot iff rel in [0,8)
            unsigned long long sh = 0x3F80ull << ((rel & 3) << 4);  // bf16 1.0
            af[mi].u[0] = (rel < 4u) ? sh : 0ull;
            af[mi].u[1] = ((rel - 4u) < 4u) ? sh : 0ull;
        }
        #pragma unroll
        for (int mi = 0; mi < 4; mi++)
            #pragma unroll
            for (int ni = 0; ni < 8; ni++)
                acc[mi][ni] = __builtin_amdgcn_mfma_f32_16x16x32_bf16(
                    af[mi].v, bf[ni].v, acc[mi][ni], 0, 0, 0);
    };

    if (!STAGE_FP32) {
        // prologue: idx(4) + stage0(8) + stage1(8) = 20 issued; vmcnt(8) retires
        // the 12 oldest (idx + tile0), tile1's 8 stay in flight.
        stageIdx();
        stageB(bsh0, 0);
        stageB(bsh1, BKT);
        asm volatile("s_waitcnt vmcnt(8)" ::: "memory");
        __builtin_amdgcn_s_barrier();
        __builtin_amdgcn_sched_barrier(0);

        ABFrag bfA[8], bfB[8];
        bfRead(bsh0, 0, bfA);              // software-pipeline prologue: tile0 s0
        __builtin_amdgcn_sched_barrier(0);

        for (int tt = 0; tt < NT; tt++) {
            const int kb = tt * BKT;
            unsigned char* cur = (tt & 1) ? bsh1 : bsh0;
            unsigned char* nxt = (tt & 1) ? bsh0 : bsh1;
            // [A] idx words + s1 frag reads (bfA in flight since last iter's [P])
            unsigned int w0 = wRead(kb, 0);
            bfRead(cur, 1, bfB);
            unsigned int w1 = wRead(kb, 1);
            __builtin_amdgcn_sched_barrier(0);
            // [D0] s0 cluster — compiler waits (counted lgkm) for bfA/w0 only
            __builtin_amdgcn_s_setprio(1);
            mfmaPhase(bfA, w0);
            __builtin_amdgcn_s_setprio(0);
            asm volatile("s_waitcnt lgkmcnt(0)" ::: "memory");
            __builtin_amdgcn_sched_barrier(0);
            // [W] retire tile tt+1's staging (issued a full tile ago at [C] of
            //     tt-1; covered by [P]+[D1]+[A]+[D0] — near-free drain)
            asm volatile("s_waitcnt vmcnt(0)" ::: "memory");
            // [B] single barrier: all waves' reads of cur done (lgkm0 above) ->
            //     overwrite safe; all waves' tile tt+1 loads retired -> [P] safe
            __builtin_amdgcn_s_barrier();
            __builtin_amdgcn_sched_barrier(0);
            // [C] restage cur with tile tt+2 (issue only; retired at [W] of tt+1)
            if (tt + 2 < NT) stageB(cur, kb + 2 * BKT);
            __builtin_amdgcn_sched_barrier(0);
            // [P] cross-tile prefetch: tile tt+1 s0 frags from nxt (visible since [B])
            if (tt + 1 < NT) bfRead(nxt, 0, bfA);
            __builtin_amdgcn_sched_barrier(0);
            // [D1] s1 cluster (covers [C] staging latency + [P] read latency)
            __builtin_amdgcn_s_setprio(1);
            mfmaPhase(bfB, w1);
            __builtin_amdgcn_s_setprio(0);
            __builtin_amdgcn_sched_barrier(0);
        }
    } else {
        // Fallback (no workspace for lutb): single-buffer loop, convert on stage.
        stageIdx();
        asm volatile("s_waitcnt vmcnt(0)" ::: "memory");
        __syncthreads();
        ABFrag bfx[8];
        for (int tt = 0; tt < NT; tt++) {
            const int kb = tt * BKT;
            stageB32(bsh0, kb);
            __syncthreads();
            #pragma unroll
            for (int s = 0; s < 2; s++) {
                bfRead(bsh0, s, bfx);
                mfmaPhase(bfx, wRead(kb, s));
            }
            __syncthreads();
        }
    }

    // --- epilogue: MFMA row m = q*4 + r -> global row = m0 + wm*64 + 4*m + mi ---
    #pragma unroll
    for (int mi = 0; mi < 4; mi++) {
        #pragma unroll
        for (int ni = 0; ni < 8; ni++) {
            const int col = n0 + wn * 128 + ni * 16 + l15;
            #pragma unroll
            for (int r = 0; r < 4; r++) {
                const int row = m0 + wm * 64 + 4 * (q * 4 + r) + mi;
                out[(size_t)row * OUT_F + col] = acc[mi][ni][r];
            }
        }
    }
}

extern "C" void kernel_launch(void* const* d_in, const int* in_sizes, int n_in,
                              void* d_out, int out_size, void* d_ws, size_t ws_size,
                              hipStream_t stream) {
    const float* input = (const float*)d_in[0];
    const int*   dims  = (const int*)d_in[1];
    // d_in[2] selection_matrix, d_in[4] tree_des_mat: structure folded into the kernels
    const float* thr   = (const float*)d_in[3];
    const float* lut   = (const float*)d_in[5];
    float* out = (float*)d_out;

    const size_t lutbBytes = (size_t)OUT_F * KDIM * 2;       // 32 MB
    const size_t idxBytes  = (size_t)(C_CB / 2) * N_ROWS;    // 512 KB

    const int nblocks = (OUT_F / BN) * (N_ROWS / BM);        // 16 x 32 = 512

    if (ws_size >= lutbBytes + idxBytes) {
        unsigned short* lutb = (unsigned short*)d_ws;
        unsigned char*  idx4 = (unsigned char*)d_ws + lutbBytes;
        k_prep<<<N_ROWS + CVT_BLOCKS, 256, 0, stream>>>(input, dims, thr, idx4, lut, lutb);
        k_gemm<false><<<nblocks, 256, 0, stream>>>(lutb, lut, idx4, out);
    } else {
        unsigned char* idx4 = (unsigned char*)d_ws;
        k_prep<<<N_ROWS, 256, 0, stream>>>(input, dims, thr, idx4, lut, nullptr);
        k_gemm<true><<<nblocks, 256, 0, stream>>>(nullptr, lut, idx4, out);
    }
}

// Round 10
// 280.696 us; speedup vs baseline: 1.0654x; 1.0353x over previous
//
#include <hip/hip_runtime.h>

#define N_ROWS 4096
#define IN_F   4096
#define OUT_F  4096
#define C_CB   256
#define KDIM   4096   // C_CB * 16

typedef short bf16x8 __attribute__((ext_vector_type(8)));
typedef float f32x4  __attribute__((ext_vector_type(4)));

union ABFrag { unsigned long long u[2]; bf16x8 v; };

__device__ __forceinline__ unsigned int f2bf(float f) {
    unsigned int u = __builtin_bit_cast(unsigned int, f);
    return (u + 0x7FFFu + ((u >> 16) & 1u)) >> 16;   // RNE
}

// ---------------- Kernel 1: fused prep ----------------
// blocks [0, N_ROWS): tree descent, R3-proven LDS-staged gather form
// blocks [N_ROWS, N_ROWS+CVT_BLOCKS): lut fp32 -> bf16
// Fused residual ~34us (R7/R9 twice-confirmed) vs ~45 separate.
#define CVT_BLOCKS ((OUT_F * KDIM) / (256 * 8))   // 8192

__global__ __launch_bounds__(256) void k_prep(const float* __restrict__ input,
                                              const int* __restrict__ dims,
                                              const float* __restrict__ thr,
                                              unsigned char* __restrict__ idx4,
                                              const float* __restrict__ lut,
                                              unsigned short* __restrict__ lutb) {
    __shared__ float rowS[IN_F];         // 16 KB
    __shared__ float thrS[C_CB * 15];    // 15 KB
    __shared__ int   dimS[C_CB * 4];     // 4 KB
    const int b = blockIdx.x;
    const int t = threadIdx.x;

    if (b < N_ROWS) {
        const int n = b;
        #pragma unroll
        for (int i = 0; i < 4; i++) dimS[i * 256 + t] = dims[i * 256 + t];
        #pragma unroll
        for (int i = 0; i < 15; i++) thrS[i * 256 + t] = thr[i * 256 + t];
        const float* row = input + (size_t)n * IN_F;
        #pragma unroll
        for (int i = 0; i < 4; i++) {
            float4 v = *(const float4*)(row + i * 1024 + t * 4);
            *(float4*)(rowS + i * 1024 + t * 4) = v;
        }
        __syncthreads();

        const int c = t;
        int4 d = *(const int4*)(dimS + c * 4);
        const float* th = thrS + c * 15;
        float x0 = rowS[d.x], x1 = rowS[d.y], x2 = rowS[d.z], x3 = rowS[d.w];
        int b0 = x0 > th[0];
        int j1 = 1 + b0;
        int b1 = x1 > th[j1];
        int j2 = 2 * j1 + 1 + b1;
        int b2 = x2 > th[j2];
        int j3 = 2 * j2 + 1 + b2;
        int b3 = x3 > th[j3];
        int idx = (b0 << 3) | (b1 << 2) | (b2 << 1) | b3;
        int other = __shfl_xor(idx, 1);
        if (!(c & 1))
            idx4[(c >> 1) * N_ROWS + n] = (unsigned char)(idx | (other << 4));
    } else {
        const int i = ((b - N_ROWS) * 256 + t) * 8;
        float4 a = *(const float4*)(lut + i);
        float4 f = *(const float4*)(lut + i + 4);
        uint4 o;
        o.x = f2bf(a.x) | (f2bf(a.y) << 16);
        o.y = f2bf(a.z) | (f2bf(a.w) << 16);
        o.z = f2bf(f.x) | (f2bf(f.y) << 16);
        o.w = f2bf(f.z) | (f2bf(f.w) << 16);
        *(uint4*)(lutb + i) = o;
    }
}

// ---------------- Kernel 2: GEMM with implicit one-hot A ----------------
// out[n][k] = sum_c lut[k][c][idx[n][c]]
// R6 measured-best schedule (97us: two barriers/tile, counted vmcnt(8) never
// waiting on loads younger than a full tile, phase-split setprio clusters,
// 0 bank conflicts). R9's single-barrier+vmcnt(0) drain falsified (-14us).
// This round's single delta: DUAL-PHASE READ ISSUE — both phases' ds_read
// groups issued back-to-back (pinned by sched_barrier), compiler inserts the
// counted lgkmcnt(9) before the s0 cluster, so s0's latency hides under s1's
// issue and s1's under the s0 MFMA cluster. No read batch is exposed.
#define BM 128
#define BN 256
#define BKT 64          // kdim per LDS stage (2 MFMA K-steps of 32)
#define BSTAGE (BN * BKT * 2)   // 32 KB per B buffer
#define NT (KDIM / BKT)         // 64 tiles

template<bool STAGE_FP32>
__global__ __launch_bounds__(256, 2) void k_gemm(const unsigned short* __restrict__ lutb,
                                                 const float* __restrict__ lutf,
                                                 const unsigned char* __restrict__ idx4,
                                                 float* __restrict__ out) {
    __shared__ unsigned char smem[16384 + 2 * BSTAGE];   // idx 16KB + 2x B 32KB = 80 KB
    unsigned char* ish  = smem;                          // [cbp 128][row 128]
    unsigned char* bsh0 = smem + 16384;
    unsigned char* bsh1 = smem + 16384 + BSTAGE;

    const int t   = threadIdx.x;
    const int l15 = t & 15;
    const int q   = (t >> 4) & 3;          // quad within wave
    const int w   = t >> 6;
    const int wm  = w >> 1, wn = w & 1;    // 2x2 waves -> 64x128 tile each

    // XCD swizzle: XCD = bid&7 owns 2 consecutive n-panels x all 32 m-blocks.
    const int bid = blockIdx.x;            // 512 blocks = 16 bx x 32 by
    const int bx  = ((bid & 7) << 1) | ((bid >> 3) & 1);   // n-block 0..15
    const int by  = bid >> 4;                              // m-block 0..31
    const int m0  = by * BM;
    const int n0  = bx * BN;

    // --- idx staging: full [cbp 128][row 128] window, once in prologue ---
    auto stageIdx = [&]() {
        #pragma unroll
        for (int qq = 0; qq < 4; qq++) {
            int L = qq * 256 + t;          // 16B chunk: cbp = L>>3, row-part = L&7
            const unsigned char* g = idx4 + (size_t)(L >> 3) * N_ROWS + m0 + (L & 7) * 16;
            __builtin_amdgcn_global_load_lds(
                (const __attribute__((address_space(1))) void*)g,
                (__attribute__((address_space(3))) void*)(ish + L * 16), 16, 0, 0);
        }
    };

    // --- B tile staging: [256 out-rows][64 kdim] bf16, chunk-XOR swizzled ---
    auto stageB = [&](unsigned char* dst, int kbn) {
        #pragma unroll
        for (int qq = 0; qq < 8; qq++) {
            int L = qq * 256 + t;               // 16B chunk index in LDS
            int r = L >> 3, p = L & 7;
            int c = p ^ (r & 7);                // global chunk stored at position p
            const unsigned short* g = lutb + (size_t)(n0 + r) * KDIM + kbn + c * 8;
            __builtin_amdgcn_global_load_lds(
                (const __attribute__((address_space(1))) void*)g,
                (__attribute__((address_space(3))) void*)(dst + L * 16), 16, 0, 0);
        }
    };
    auto stageB32 = [&](unsigned char* dst, int kbn) {
        #pragma unroll
        for (int qq = 0; qq < 8; qq++) {
            int L = qq * 256 + t;
            int r = L >> 3, p = L & 7;
            int c = p ^ (r & 7);
            const float* g = lutf + (size_t)(n0 + r) * KDIM + kbn + c * 8;
            float4 f0 = *(const float4*)g;
            float4 f1 = *(const float4*)(g + 4);
            uint4 o;
            o.x = f2bf(f0.x) | (f2bf(f0.y) << 16);
            o.y = f2bf(f0.z) | (f2bf(f0.w) << 16);
            o.z = f2bf(f1.x) | (f2bf(f1.y) << 16);
            o.w = f2bf(f1.z) | (f2bf(f1.w) << 16);
            *(uint4*)(dst + L * 16) = o;
        }
    };

    f32x4 acc[4][8];
    #pragma unroll
    for (int mi = 0; mi < 4; mi++)
        #pragma unroll
        for (int ni = 0; ni < 8; ni++)
            acc[mi][ni] = (f32x4){0.f, 0.f, 0.f, 0.f};

    const int xorv = l15 & 7;                       // B chunk swizzle key
    const int bRowByte = (wn * 128 + l15) * (BKT * 2);
    const int aByte = wm * 64 + l15 * 4;            // idx word offset within a cbp row
    const int qh4  = (q >> 1) * 4;                  // nibble select: cb c0 vs c0+1
    const unsigned int sub8 = (q & 1) << 3;         // window offset within codebook

    // B fragment reads for phase s: 8 x ds_read_b128 (swizzled chunk)
    auto bfRead = [&](const unsigned char* src, int s, ABFrag (&bf)[8]) {
        const int chunkOff = ((s * 4 + q) ^ xorv) * 16;
        #pragma unroll
        for (int ni = 0; ni < 8; ni++)
            bf[ni].v = *(const bf16x8*)(src + bRowByte + ni * (16 * BKT * 2) + chunkOff);
    };
    // idx word for phase s of tile at kb (full window: cbp in [0,128))
    auto wRead = [&](int kb, int s) {
        return *(const unsigned int*)(ish + ((kb >> 5) + s) * 128 + aByte);
    };
    // per-phase MFMA cluster: build 4 one-hot A frags, 32 MFMAs
    auto mfmaPhase = [&](const ABFrag (&bf)[8], unsigned int w32) {
        ABFrag af[4];
        #pragma unroll
        for (int mi = 0; mi < 4; mi++) {
            unsigned int T = (w32 >> (mi * 8 + qh4)) & 0xFu;
            unsigned int rel = T - sub8;                    // one-hot iff rel in [0,8)
            unsigned long long sh = 0x3F80ull << ((rel & 3) << 4);  // bf16 1.0
            af[mi].u[0] = (rel < 4u) ? sh : 0ull;
            af[mi].u[1] = ((rel - 4u) < 4u) ? sh : 0ull;
        }
        #pragma unroll
        for (int mi = 0; mi < 4; mi++)
            #pragma unroll
            for (int ni = 0; ni < 8; ni++)
                acc[mi][ni] = __builtin_amdgcn_mfma_f32_16x16x32_bf16(
                    af[mi].v, bf[ni].v, acc[mi][ni], 0, 0, 0);
    };

    if (!STAGE_FP32) {
        // prologue: idx(4) + stage0(8) + stage1(8) = 20 issued; vmcnt(8) retires
        // the 12 oldest (idx + tile0), tile1's 8 stay in flight.
        stageIdx();
        stageB(bsh0, 0);
        stageB(bsh1, BKT);
        asm volatile("s_waitcnt vmcnt(8)" ::: "memory");
        __builtin_amdgcn_s_barrier();
        __builtin_amdgcn_sched_barrier(0);

        ABFrag bf0[8], bf1[8];
        for (int tt = 0; tt < NT; tt++) {
            const int kb = tt * BKT;
            unsigned char* cur = (tt & 1) ? bsh1 : bsh0;
            // [A] dual-phase issue: s0 group (9 lgkm ops), pin, s1 group (9 more).
            //     Compiler inserts counted lgkmcnt before the s0 cluster, so s0's
            //     latency hides under s1's issue.
            unsigned int w0 = wRead(kb, 0);
            bfRead(cur, 0, bf0);
            __builtin_amdgcn_sched_barrier(0);
            bfRead(cur, 1, bf1);
            unsigned int w1 = wRead(kb, 1);
            __builtin_amdgcn_sched_barrier(0);
            // [D0] s0 cluster (s1 reads retire underneath)
            __builtin_amdgcn_s_setprio(1);
            mfmaPhase(bf0, w0);
            __builtin_amdgcn_s_setprio(0);
            // all reads of cur retired before other waves may overwrite it
            asm volatile("s_waitcnt lgkmcnt(0)" ::: "memory");
            __builtin_amdgcn_sched_barrier(0);
            // [B] all waves done reading cur -> overwrite safe
            __builtin_amdgcn_s_barrier();
            __builtin_amdgcn_sched_barrier(0);
            // [C] restage cur with tile tt+2 (issue only; no wait here)
            if (tt + 2 < NT) stageB(cur, kb + 2 * BKT);
            __builtin_amdgcn_sched_barrier(0);
            // [D1] s1 cluster (staging loads fly underneath)
            __builtin_amdgcn_s_setprio(1);
            mfmaPhase(bf1, w1);
            __builtin_amdgcn_s_setprio(0);
            // [E] counted wait: tile tt+1's 8 loads done (issued a full tile ago);
            //     tt+2's 8 newest stay in flight
            if (tt + 2 < NT) asm volatile("s_waitcnt vmcnt(8)" ::: "memory");
            else             asm volatile("s_waitcnt vmcnt(0)" ::: "memory");
            // [F] staging writes visible to all waves before next iteration reads
            __builtin_amdgcn_s_barrier();
            __builtin_amdgcn_sched_barrier(0);
        }
    } else {
        // Fallback (no workspace for lutb): single-buffer loop, convert on stage.
        stageIdx();
        asm volatile("s_waitcnt vmcnt(0)" ::: "memory");
        __syncthreads();
        ABFrag bfx[8];
        for (int tt = 0; tt < NT; tt++) {
            const int kb = tt * BKT;
            stageB32(bsh0, kb);
            __syncthreads();
            #pragma unroll
            for (int s = 0; s < 2; s++) {
                bfRead(bsh0, s, bfx);
                mfmaPhase(bfx, wRead(kb, s));
            }
            __syncthreads();
        }
    }

    // --- epilogue: MFMA row m = q*4 + r -> global row = m0 + wm*64 + 4*m + mi ---
    #pragma unroll
    for (int mi = 0; mi < 4; mi++) {
        #pragma unroll
        for (int ni = 0; ni < 8; ni++) {
            const int col = n0 + wn * 128 + ni * 16 + l15;
            #pragma unroll
            for (int r = 0; r < 4; r++) {
                const int row = m0 + wm * 64 + 4 * (q * 4 + r) + mi;
                out[(size_t)row * OUT_F + col] = acc[mi][ni][r];
            }
        }
    }
}

extern "C" void kernel_launch(void* const* d_in, const int* in_sizes, int n_in,
                              void* d_out, int out_size, void* d_ws, size_t ws_size,
                              hipStream_t stream) {
    const float* input = (const float*)d_in[0];
    const int*   dims  = (const int*)d_in[1];
    // d_in[2] selection_matrix, d_in[4] tree_des_mat: structure folded into the kernels
    const float* thr   = (const float*)d_in[3];
    const float* lut   = (const float*)d_in[5];
    float* out = (float*)d_out;

    const size_t lutbBytes = (size_t)OUT_F * KDIM * 2;       // 32 MB
    const size_t idxBytes  = (size_t)(C_CB / 2) * N_ROWS;    // 512 KB

    const int nblocks = (OUT_F / BN) * (N_ROWS / BM);        // 16 x 32 = 512

    if (ws_size >= lutbBytes + idxBytes) {
        unsigned short* lutb = (unsigned short*)d_ws;
        unsigned char*  idx4 = (unsigned char*)d_ws + lutbBytes;
        k_prep<<<N_ROWS + CVT_BLOCKS, 256, 0, stream>>>(input, dims, thr, idx4, lut, lutb);
        k_gemm<false><<<nblocks, 256, 0, stream>>>(lutb, lut, idx4, out);
    } else {
        unsigned char* idx4 = (unsigned char*)d_ws;
        k_prep<<<N_ROWS, 256, 0, stream>>>(input, dims, thr, idx4, lut, nullptr);
        k_gemm<true><<<nblocks, 256, 0, stream>>>(nullptr, lut, idx4, out);
    }
}